// Round 10
// baseline (392.675 us; speedup 1.0000x reference)
//
#include <hip/hip_runtime.h>

typedef unsigned int uint;
typedef unsigned short ushort;
typedef __attribute__((ext_vector_type(8))) short bf16x8;
typedef __attribute__((ext_vector_type(4))) float f32x4;

// ---------------- compile-time Clifford tables (replicates reference numpy) --------
struct GPTables {
    signed char jid[16][16];
    float       sgn[16][16];
    signed char pid[16][16];
    float       beta[16];
    signed char grade[16];
};

constexpr int popc4(int x) { return ((x >> 0) & 1) + ((x >> 1) & 1) + ((x >> 2) & 1) + ((x >> 3) & 1); }

constexpr GPTables make_tables() {
    GPTables T{};
    int blades[16] = {0, 1, 2, 4, 8, 3, 5, 6, 9, 10, 12, 7, 11, 13, 14, 15};
    int idxof[16] = {};
    for (int i = 0; i < 16; ++i) idxof[blades[i]] = i;
    float metric[4] = {1.f, -1.f, -1.f, -1.f};
    for (int i = 0; i < 16; ++i) {
        T.grade[i] = (signed char)popc4(blades[i]);
        float b = 1.f;
        for (int bit = 0; bit < 4; ++bit)
            if ((blades[i] >> bit) & 1) b *= metric[bit];
        T.beta[i] = b;
    }
    bool paths[5][5][5] = {};
    for (int a = 0; a < 16; ++a)
        for (int b = 0; b < 16; ++b)
            paths[popc4(a)][popc4(a ^ b)][popc4(b)] = true;
    int pid3[5][5][5] = {};
    int cnt = 0;
    for (int gi = 0; gi < 5; ++gi)
        for (int gj = 0; gj < 5; ++gj)
            for (int gk = 0; gk < 5; ++gk)
                if (paths[gi][gj][gk]) pid3[gi][gj][gk] = cnt++;
    for (int ii = 0; ii < 16; ++ii) {
        for (int kk = 0; kk < 16; ++kk) {
            int a = blades[ii], b = blades[kk];
            int c = a ^ b;
            int s = 0, t = a >> 1;
            while (t) { s += popc4(t & b); t >>= 1; }
            float sign = (s & 1) ? -1.f : 1.f;
            for (int bit = 0; bit < 4; ++bit)
                if (((a >> bit) & 1) && ((b >> bit) & 1)) sign *= metric[bit];
            T.jid[ii][kk] = (signed char)idxof[c];
            T.sgn[ii][kk] = sign;
            T.pid[ii][kk] = (signed char)pid3[popc4(a)][popc4(c)][popc4(b)];
        }
    }
    return T;
}

constexpr GPTables TBL = make_tables();

// sizes
#define BF (4096)
#define FF (512)
#define BM_ (2097152)   // BF*FF
#define FFFF (262144)   // FF*FF

__device__ inline ushort f2bf(float f) {
    uint u = __float_as_uint(f);
    uint r = (u + 0x7fffu + ((u >> 16) & 1u)) >> 16;
    return (ushort)r;
}
__device__ inline float bf2f(ushort h) { return __uint_as_float(((uint)h) << 16); }

typedef __attribute__((address_space(3))) uint lds_u32;
typedef const __attribute__((address_space(1))) uint g_u32;
__device__ __forceinline__ void gload16(const void* gsrc, void* ldst) {
    __builtin_amdgcn_global_load_lds((g_u32*)gsrc, (lds_u32*)ldst, 16, 0, 0);
}

// ---------------- kernel 1: transpose + split-cast x -> Xh/Xl [16][BM_] ------------
__global__ __launch_bounds__(256) void k_transpose_x(const float* __restrict__ x,
                                                     ushort* __restrict__ Xh,
                                                     ushort* __restrict__ Xl) {
    const int p0 = (blockIdx.x * 256 + threadIdx.x) * 2;
    float v[32];
    const float4* x4 = (const float4*)(x + (size_t)p0 * 16);
#pragma unroll
    for (int j = 0; j < 8; ++j) {
        float4 t = x4[j];
        v[j * 4 + 0] = t.x; v[j * 4 + 1] = t.y; v[j * 4 + 2] = t.z; v[j * 4 + 3] = t.w;
    }
#pragma unroll
    for (int i = 0; i < 16; ++i) {
        ushort h0 = f2bf(v[i]),      h1 = f2bf(v[16 + i]);
        ushort l0 = f2bf(v[i] - bf2f(h0));
        ushort l1 = f2bf(v[16 + i] - bf2f(h1));
        *(uint*)&Xh[(size_t)i * BM_ + p0] = (uint)h0 | ((uint)h1 << 16);
        *(uint*)&Xl[(size_t)i * BM_ + p0] = (uint)l0 | ((uint)l1 << 16);
    }
}

// ---------------- kernel 2: pack weights -> Wb[15][512][512] bf16 ------------------
// planes 0..4 right_hi, 5..9 right_lo, 10..14 left (per grade)
__global__ __launch_bounds__(256) void k_prep_w(const float* __restrict__ w_right,
                                                const float* __restrict__ w_left,
                                                ushort* __restrict__ Wb) {
    const int n = blockIdx.x;
    const int m = threadIdx.x * 2;
#pragma unroll
    for (int g = 0; g < 5; ++g) {
        float a = w_right[(size_t)n * (FF * 5) + (size_t)m * 5 + g];
        float b = w_right[(size_t)n * (FF * 5) + (size_t)(m + 1) * 5 + g];
        ushort ah = f2bf(a), bh = f2bf(b);
        ushort al = f2bf(a - bf2f(ah)), bl = f2bf(b - bf2f(bh));
        *(uint*)&Wb[(size_t)g * FFFF + (size_t)n * FF + m] = (uint)ah | ((uint)bh << 16);
        *(uint*)&Wb[(size_t)(5 + g) * FFFF + (size_t)n * FF + m] = (uint)al | ((uint)bl << 16);
        float c = w_left[(size_t)n * (FF * 5) + (size_t)m * 5 + g];
        float d = w_left[(size_t)n * (FF * 5) + (size_t)(m + 1) * 5 + g];
        *(uint*)&Wb[(size_t)(10 + g) * FFFF + (size_t)n * FF + m] =
            (uint)f2bf(c) | ((uint)f2bf(d) << 16);
    }
}

// ---------------- kernel 2b: transpose per-n tables for k_gp -----------------------
// gpwT[35][512], sigT[5][512] (pre-sigmoided a_norm)
__global__ __launch_bounds__(256) void k_prep_tables(const float* __restrict__ gpw,
                                                     const float* __restrict__ a_norm,
                                                     float* __restrict__ gpwT,
                                                     float* __restrict__ sigT) {
    const int n = blockIdx.x * 256 + threadIdx.x;  // grid 2 x 256
#pragma unroll
    for (int p = 0; p < 35; ++p) gpwT[(size_t)p * FF + n] = gpw[(size_t)n * 35 + p];
#pragma unroll
    for (int g = 0; g < 5; ++g)
        sigT[(size_t)g * FF + n] = 1.f / (1.f + __expf(-a_norm[(size_t)n * 5 + g]));
}

// ---------------- kernel 3: merged GEMM, 2-phase prefetch double-buffer ------------
// (round-5/7 proven version: 5 planes in LDS, dbuf 2x40KB, syncthreads drain)
__device__ __forceinline__ bf16x8 ldfrag(const ushort* tile, int row, int colb) {
    return *(const bf16x8*)((const char*)tile + row * 64 + (colb ^ (((row >> 2) & 3) << 4)));
}

__global__ __launch_bounds__(256, 2) void k_gemm(const ushort* __restrict__ Xh,
                                                 const ushort* __restrict__ Xl,
                                                 const ushort* __restrict__ Wb,
                                                 float* __restrict__ OutR,
                                                 ushort* __restrict__ OutL) {
    const int comp = blockIdx.z;
    const int g = TBL.grade[comp];
    const ushort* Ah = Xh + (size_t)comp * BM_;
    const ushort* Al = Xl + (size_t)comp * BM_;
    const ushort* Bh = Wb + (size_t)g * FFFF;
    const ushort* Bl = Wb + (size_t)(5 + g) * FFFF;
    const ushort* BL = Wb + (size_t)(10 + g) * FFFF;
    const int m0 = blockIdx.x * 128;
    const int n0 = blockIdx.y * 128;

    __shared__ ushort sh[2 * 5 * 4096];  // 81920 B

    const int tid = threadIdx.x;
    const int lane = tid & 63, wid = tid >> 6;
    const int wm = wid >> 1, wn = wid & 1;
    const int lr = lane & 15;
    const int kb = (lane >> 4) * 16;  // byte col of 16B k-slice

    const size_t mb_ = (size_t)m0 * (FF * 2), nb_ = (size_t)n0 * (FF * 2);

    auto stage = [&](int buf, int k0) {
#pragma unroll
        for (int pass = 0; pass < 2; ++pass) {
            const int c = tid + pass * 256;                       // 0..511 chunk id
            const int row = c >> 2;
            const int scb = ((c & 3) * 16) ^ (((c >> 4) & 3) << 4);  // pre-swizzled src slot
            const size_t gb = (size_t)row * (FF * 2) + (size_t)k0 * 2 + scb;
            char* dst = (char*)sh + buf * 40960 + c * 16;
            gload16((const char*)Ah + mb_ + gb, dst);
            gload16((const char*)Al + mb_ + gb, dst + 8192);
            gload16((const char*)Bh + nb_ + gb, dst + 16384);
            gload16((const char*)Bl + nb_ + gb, dst + 24576);
            gload16((const char*)BL + nb_ + gb, dst + 32768);
        }
    };

    f32x4 accR[4][4] = {};
    f32x4 accL[4][4] = {};

    stage(0, 0);
    __syncthreads();

    for (int t = 0; t < 16; ++t) {
        const ushort* sb = sh + (t & 1) * 20480;
        if (t < 15) stage((t + 1) & 1, (t + 1) * 32);  // issue next-tile loads FIRST

        const ushort* tA  = sb;
        const ushort* tAl = sb + 1 * 4096;
        const ushort* tBh = sb + 2 * 4096;
        const ushort* tBl = sb + 3 * 4096;
        const ushort* tBL = sb + 4 * 4096;

        bf16x8 ah[4], al[4], bh[4], bl[4], bLf[4];
#pragma unroll
        for (int mb = 0; mb < 4; ++mb) {
            ah[mb] = ldfrag(tA,  wm * 64 + mb * 16 + lr, kb);
            al[mb] = ldfrag(tAl, wm * 64 + mb * 16 + lr, kb);
        }
#pragma unroll
        for (int nb = 0; nb < 4; ++nb) {
            bh[nb]  = ldfrag(tBh, wn * 64 + nb * 16 + lr, kb);
            bl[nb]  = ldfrag(tBl, wn * 64 + nb * 16 + lr, kb);
            bLf[nb] = ldfrag(tBL, wn * 64 + nb * 16 + lr, kb);
        }
#pragma unroll
        for (int mb = 0; mb < 4; ++mb)
#pragma unroll
            for (int nb = 0; nb < 4; ++nb) {
                accR[mb][nb] = __builtin_amdgcn_mfma_f32_16x16x32_bf16(ah[mb], bh[nb],  accR[mb][nb], 0, 0, 0);
                accR[mb][nb] = __builtin_amdgcn_mfma_f32_16x16x32_bf16(ah[mb], bl[nb],  accR[mb][nb], 0, 0, 0);
                accR[mb][nb] = __builtin_amdgcn_mfma_f32_16x16x32_bf16(al[mb], bh[nb],  accR[mb][nb], 0, 0, 0);
                accL[mb][nb] = __builtin_amdgcn_mfma_f32_16x16x32_bf16(ah[mb], bLf[nb], accL[mb][nb], 0, 0, 0);
            }
        __syncthreads();  // drains this iter's stage (vmcnt) + all ds_reads (lgkm)
    }

    float* CR = OutR + (size_t)comp * BM_;
    ushort* CL = OutL + (size_t)comp * BM_;
#pragma unroll
    for (int mb = 0; mb < 4; ++mb)
#pragma unroll
        for (int nb = 0; nb < 4; ++nb) {
            int row = m0 + wm * 64 + mb * 16 + (lane >> 4) * 4;
            int col = n0 + wn * 64 + nb * 16 + (lane & 15);
#pragma unroll
            for (int r = 0; r < 4; ++r) {
                CR[(size_t)(row + r) * FF + col] = accR[mb][nb][r];
                CL[(size_t)(row + r) * FF + col] = f2bf(accL[mb][nb][r]);
            }
        }
}

// ---------------- kernel 4: normalize(right) + Cayley gp + left + bias, scale ------
// 4-way b-amortized: per-n tables loaded once per thread, 4 outputs processed
// SEQUENTIALLY with per-iteration locals (register-footprint-neutral vs 2-way).
__global__ __launch_bounds__(256) void k_gp(const float* __restrict__ x,
                                            const float* __restrict__ OutR,
                                            const ushort* __restrict__ OutL,
                                            const float* __restrict__ gpwT,
                                            const float* __restrict__ sigT,
                                            const float* __restrict__ b_left,
                                            float* __restrict__ out) {
    const int t0 = blockIdx.x * 256 + threadIdx.x;  // 0 .. BM_/4-1
    const int n = t0 & (FF - 1);

    float pw[35];
#pragma unroll
    for (int p = 0; p < 35; ++p) pw[p] = gpwT[(size_t)p * FF + n];
    float sg[5];
#pragma unroll
    for (int g = 0; g < 5; ++g) sg[g] = sigT[(size_t)g * FF + n];
    const float bl = b_left[n];

#pragma unroll
    for (int u = 0; u < 4; ++u) {
        const int bn = t0 + u * (BM_ / 4);

        float xi[16];
        {
            const float4* xp = (const float4*)(x + (size_t)bn * 16);
#pragma unroll
            for (int j = 0; j < 4; ++j) {
                float4 t = xp[j];
                xi[j * 4 + 0] = t.x; xi[j * 4 + 1] = t.y; xi[j * 4 + 2] = t.z; xi[j * 4 + 3] = t.w;
            }
        }

        float R[16];
#pragma unroll
        for (int i = 0; i < 16; ++i) R[i] = OutR[(size_t)i * BM_ + bn];

        float q[5] = {0.f, 0.f, 0.f, 0.f, 0.f};
#pragma unroll
        for (int i = 0; i < 16; ++i) q[TBL.grade[i]] += TBL.beta[i] * R[i] * R[i];
        float inv[5];
#pragma unroll
        for (int g = 0; g < 5; ++g) {
            float nr = sqrtf(fabsf(q[g]));
            float nf = sg[g] * (nr - 1.f) + 1.f + 1e-6f;
            inv[g] = 1.f / nf;
        }
#pragma unroll
        for (int i = 0; i < 16; ++i) R[i] *= inv[TBL.grade[i]];

        float acc[16] = {};
#pragma unroll
        for (int ii = 0; ii < 16; ++ii) {
#pragma unroll
            for (int kk = 0; kk < 16; ++kk) {
                const int j = TBL.jid[ii][kk];
                const int p = TBL.pid[ii][kk];
                const float s = TBL.sgn[ii][kk];
                acc[j] += (s * pw[p]) * (xi[ii] * R[kk]);
            }
        }

        float o[16];
#pragma unroll
        for (int j = 0; j < 16; ++j) {
            float l = bf2f(OutL[(size_t)j * BM_ + bn]);
            if (j == 0) l += bl;
            o[j] = (l + acc[j]) * 0.70710678118654752440f;
        }
        float4* op = (float4*)(out + (size_t)bn * 16);
#pragma unroll
        for (int j = 0; j < 4; ++j) {
            float4 t;
            t.x = o[j * 4 + 0]; t.y = o[j * 4 + 1]; t.z = o[j * 4 + 2]; t.w = o[j * 4 + 3];
            op[j] = t;
        }
    }
}

extern "C" void kernel_launch(void* const* d_in, const int* in_sizes, int n_in,
                              void* d_out, int out_size, void* d_ws, size_t ws_size,
                              hipStream_t stream) {
    (void)in_sizes; (void)n_in; (void)out_size; (void)ws_size;
    const float* x       = (const float*)d_in[0];
    const float* w_left  = (const float*)d_in[1];
    const float* b_left  = (const float*)d_in[2];
    const float* w_right = (const float*)d_in[3];
    const float* a_norm  = (const float*)d_in[4];
    const float* gpw     = (const float*)d_in[5];
    float* out = (float*)d_out;

    char* ws = (char*)d_ws;
    ushort* Xh   = (ushort*)ws;                        //  67,108,864 B
    ushort* Xl   = (ushort*)(ws + 67108864);           //  67,108,864 B
    ushort* Wb   = (ushort*)(ws + 134217728);          //   7,864,320 B
    float*  OutR = (float*)(ws + 142082048);           // 134,217,728 B
    ushort* OutL = (ushort*)(ws + 276299776);          //  67,108,864 B
    // gpwT/sigT overwrite the (then-dead) Xh region after k_gemm finishes
    float*  gpwT = (float*)ws;                         //  71,680 B
    float*  sigT = (float*)(ws + 71680);               //  10,240 B

    k_transpose_x<<<4096, 256, 0, stream>>>(x, Xh, Xl);
    k_prep_w<<<512, 256, 0, stream>>>(w_right, w_left, Wb);
    dim3 g(32, 4, 16);
    k_gemm<<<g, 256, 0, stream>>>(Xh, Xl, Wb, OutR, OutL);
    k_prep_tables<<<2, 256, 0, stream>>>(gpw, a_norm, gpwT, sigT);
    k_gp<<<2048, 256, 0, stream>>>(x, OutR, OutL, gpwT, sigT, b_left, out);
}

// Round 11
// 338.230 us; speedup vs baseline: 1.1610x; 1.1610x over previous
//
#include <hip/hip_runtime.h>

typedef unsigned int uint;
typedef unsigned short ushort;
typedef __attribute__((ext_vector_type(8))) short bf16x8;
typedef __attribute__((ext_vector_type(4))) float f32x4;

// ---------------- compile-time Clifford tables (replicates reference numpy) --------
struct GPTables {
    signed char jid[16][16];
    float       sgn[16][16];
    signed char pid[16][16];
    float       beta[16];
    signed char grade[16];
};

constexpr int popc4(int x) { return ((x >> 0) & 1) + ((x >> 1) & 1) + ((x >> 2) & 1) + ((x >> 3) & 1); }

constexpr GPTables make_tables() {
    GPTables T{};
    int blades[16] = {0, 1, 2, 4, 8, 3, 5, 6, 9, 10, 12, 7, 11, 13, 14, 15};
    int idxof[16] = {};
    for (int i = 0; i < 16; ++i) idxof[blades[i]] = i;
    float metric[4] = {1.f, -1.f, -1.f, -1.f};
    for (int i = 0; i < 16; ++i) {
        T.grade[i] = (signed char)popc4(blades[i]);
        float b = 1.f;
        for (int bit = 0; bit < 4; ++bit)
            if ((blades[i] >> bit) & 1) b *= metric[bit];
        T.beta[i] = b;
    }
    bool paths[5][5][5] = {};
    for (int a = 0; a < 16; ++a)
        for (int b = 0; b < 16; ++b)
            paths[popc4(a)][popc4(a ^ b)][popc4(b)] = true;
    int pid3[5][5][5] = {};
    int cnt = 0;
    for (int gi = 0; gi < 5; ++gi)
        for (int gj = 0; gj < 5; ++gj)
            for (int gk = 0; gk < 5; ++gk)
                if (paths[gi][gj][gk]) pid3[gi][gj][gk] = cnt++;
    for (int ii = 0; ii < 16; ++ii) {
        for (int kk = 0; kk < 16; ++kk) {
            int a = blades[ii], b = blades[kk];
            int c = a ^ b;
            int s = 0, t = a >> 1;
            while (t) { s += popc4(t & b); t >>= 1; }
            float sign = (s & 1) ? -1.f : 1.f;
            for (int bit = 0; bit < 4; ++bit)
                if (((a >> bit) & 1) && ((b >> bit) & 1)) sign *= metric[bit];
            T.jid[ii][kk] = (signed char)idxof[c];
            T.sgn[ii][kk] = sign;
            T.pid[ii][kk] = (signed char)pid3[popc4(a)][popc4(c)][popc4(b)];
        }
    }
    return T;
}

constexpr GPTables TBL = make_tables();

// sizes
#define BF (4096)
#define FF (512)
#define BM_ (2097152)   // BF*FF
#define FFFF (262144)   // FF*FF

__device__ inline ushort f2bf(float f) {
    uint u = __float_as_uint(f);
    uint r = (u + 0x7fffu + ((u >> 16) & 1u)) >> 16;
    return (ushort)r;
}
__device__ inline float bf2f(ushort h) { return __uint_as_float(((uint)h) << 16); }

typedef __attribute__((address_space(3))) uint lds_u32;
typedef const __attribute__((address_space(1))) uint g_u32;
__device__ __forceinline__ void gload16(const void* gsrc, void* ldst) {
    __builtin_amdgcn_global_load_lds((g_u32*)gsrc, (lds_u32*)ldst, 16, 0, 0);
}

// ---------------- kernel 1: transpose + split-cast x -> Xh/Xl [16][BM_] ------------
__global__ __launch_bounds__(256) void k_transpose_x(const float* __restrict__ x,
                                                     ushort* __restrict__ Xh,
                                                     ushort* __restrict__ Xl) {
    const int p0 = (blockIdx.x * 256 + threadIdx.x) * 2;
    float v[32];
    const float4* x4 = (const float4*)(x + (size_t)p0 * 16);
#pragma unroll
    for (int j = 0; j < 8; ++j) {
        float4 t = x4[j];
        v[j * 4 + 0] = t.x; v[j * 4 + 1] = t.y; v[j * 4 + 2] = t.z; v[j * 4 + 3] = t.w;
    }
#pragma unroll
    for (int i = 0; i < 16; ++i) {
        ushort h0 = f2bf(v[i]),      h1 = f2bf(v[16 + i]);
        ushort l0 = f2bf(v[i] - bf2f(h0));
        ushort l1 = f2bf(v[16 + i] - bf2f(h1));
        *(uint*)&Xh[(size_t)i * BM_ + p0] = (uint)h0 | ((uint)h1 << 16);
        *(uint*)&Xl[(size_t)i * BM_ + p0] = (uint)l0 | ((uint)l1 << 16);
    }
}

// ---------------- kernel 2: pack weights -> Wb[15][512][512] bf16 ------------------
// planes 0..4 right_hi, 5..9 right_lo, 10..14 left (per grade)
__global__ __launch_bounds__(256) void k_prep_w(const float* __restrict__ w_right,
                                                const float* __restrict__ w_left,
                                                ushort* __restrict__ Wb) {
    const int n = blockIdx.x;
    const int m = threadIdx.x * 2;
#pragma unroll
    for (int g = 0; g < 5; ++g) {
        float a = w_right[(size_t)n * (FF * 5) + (size_t)m * 5 + g];
        float b = w_right[(size_t)n * (FF * 5) + (size_t)(m + 1) * 5 + g];
        ushort ah = f2bf(a), bh = f2bf(b);
        ushort al = f2bf(a - bf2f(ah)), bl = f2bf(b - bf2f(bh));
        *(uint*)&Wb[(size_t)g * FFFF + (size_t)n * FF + m] = (uint)ah | ((uint)bh << 16);
        *(uint*)&Wb[(size_t)(5 + g) * FFFF + (size_t)n * FF + m] = (uint)al | ((uint)bl << 16);
        float c = w_left[(size_t)n * (FF * 5) + (size_t)m * 5 + g];
        float d = w_left[(size_t)n * (FF * 5) + (size_t)(m + 1) * 5 + g];
        *(uint*)&Wb[(size_t)(10 + g) * FFFF + (size_t)n * FF + m] =
            (uint)f2bf(c) | ((uint)f2bf(d) << 16);
    }
}

// ---------------- kernel 2b: transpose per-n tables for k_gp -----------------------
// gpwT[35][512], sigT[5][512] (pre-sigmoided a_norm)
__global__ __launch_bounds__(256) void k_prep_tables(const float* __restrict__ gpw,
                                                     const float* __restrict__ a_norm,
                                                     float* __restrict__ gpwT,
                                                     float* __restrict__ sigT) {
    const int n = blockIdx.x * 256 + threadIdx.x;  // grid 2 x 256
#pragma unroll
    for (int p = 0; p < 35; ++p) gpwT[(size_t)p * FF + n] = gpw[(size_t)n * 35 + p];
#pragma unroll
    for (int g = 0; g < 5; ++g)
        sigT[(size_t)g * FF + n] = 1.f / (1.f + __expf(-a_norm[(size_t)n * 5 + g]));
}

// ---------------- kernel 3: merged GEMM, 2-phase prefetch double-buffer ------------
// (round-5/7 proven version: 5 planes in LDS, dbuf 2x40KB, syncthreads drain)
__device__ __forceinline__ bf16x8 ldfrag(const ushort* tile, int row, int colb) {
    return *(const bf16x8*)((const char*)tile + row * 64 + (colb ^ (((row >> 2) & 3) << 4)));
}

__global__ __launch_bounds__(256, 2) void k_gemm(const ushort* __restrict__ Xh,
                                                 const ushort* __restrict__ Xl,
                                                 const ushort* __restrict__ Wb,
                                                 float* __restrict__ OutR,
                                                 ushort* __restrict__ OutL) {
    const int comp = blockIdx.z;
    const int g = TBL.grade[comp];
    const ushort* Ah = Xh + (size_t)comp * BM_;
    const ushort* Al = Xl + (size_t)comp * BM_;
    const ushort* Bh = Wb + (size_t)g * FFFF;
    const ushort* Bl = Wb + (size_t)(5 + g) * FFFF;
    const ushort* BL = Wb + (size_t)(10 + g) * FFFF;
    const int m0 = blockIdx.x * 128;
    const int n0 = blockIdx.y * 128;

    __shared__ ushort sh[2 * 5 * 4096];  // 81920 B

    const int tid = threadIdx.x;
    const int lane = tid & 63, wid = tid >> 6;
    const int wm = wid >> 1, wn = wid & 1;
    const int lr = lane & 15;
    const int kb = (lane >> 4) * 16;  // byte col of 16B k-slice

    const size_t mb_ = (size_t)m0 * (FF * 2), nb_ = (size_t)n0 * (FF * 2);

    auto stage = [&](int buf, int k0) {
#pragma unroll
        for (int pass = 0; pass < 2; ++pass) {
            const int c = tid + pass * 256;                       // 0..511 chunk id
            const int row = c >> 2;
            const int scb = ((c & 3) * 16) ^ (((c >> 4) & 3) << 4);  // pre-swizzled src slot
            const size_t gb = (size_t)row * (FF * 2) + (size_t)k0 * 2 + scb;
            char* dst = (char*)sh + buf * 40960 + c * 16;
            gload16((const char*)Ah + mb_ + gb, dst);
            gload16((const char*)Al + mb_ + gb, dst + 8192);
            gload16((const char*)Bh + nb_ + gb, dst + 16384);
            gload16((const char*)Bl + nb_ + gb, dst + 24576);
            gload16((const char*)BL + nb_ + gb, dst + 32768);
        }
    };

    f32x4 accR[4][4] = {};
    f32x4 accL[4][4] = {};

    stage(0, 0);
    __syncthreads();

    for (int t = 0; t < 16; ++t) {
        const ushort* sb = sh + (t & 1) * 20480;
        if (t < 15) stage((t + 1) & 1, (t + 1) * 32);  // issue next-tile loads FIRST

        const ushort* tA  = sb;
        const ushort* tAl = sb + 1 * 4096;
        const ushort* tBh = sb + 2 * 4096;
        const ushort* tBl = sb + 3 * 4096;
        const ushort* tBL = sb + 4 * 4096;

        bf16x8 ah[4], al[4], bh[4], bl[4], bLf[4];
#pragma unroll
        for (int mb = 0; mb < 4; ++mb) {
            ah[mb] = ldfrag(tA,  wm * 64 + mb * 16 + lr, kb);
            al[mb] = ldfrag(tAl, wm * 64 + mb * 16 + lr, kb);
        }
#pragma unroll
        for (int nb = 0; nb < 4; ++nb) {
            bh[nb]  = ldfrag(tBh, wn * 64 + nb * 16 + lr, kb);
            bl[nb]  = ldfrag(tBl, wn * 64 + nb * 16 + lr, kb);
            bLf[nb] = ldfrag(tBL, wn * 64 + nb * 16 + lr, kb);
        }
#pragma unroll
        for (int mb = 0; mb < 4; ++mb)
#pragma unroll
            for (int nb = 0; nb < 4; ++nb) {
                accR[mb][nb] = __builtin_amdgcn_mfma_f32_16x16x32_bf16(ah[mb], bh[nb],  accR[mb][nb], 0, 0, 0);
                accR[mb][nb] = __builtin_amdgcn_mfma_f32_16x16x32_bf16(ah[mb], bl[nb],  accR[mb][nb], 0, 0, 0);
                accR[mb][nb] = __builtin_amdgcn_mfma_f32_16x16x32_bf16(al[mb], bh[nb],  accR[mb][nb], 0, 0, 0);
                accL[mb][nb] = __builtin_amdgcn_mfma_f32_16x16x32_bf16(ah[mb], bLf[nb], accL[mb][nb], 0, 0, 0);
            }
        __syncthreads();  // drains this iter's stage (vmcnt) + all ds_reads (lgkm)
    }

    float* CR = OutR + (size_t)comp * BM_;
    ushort* CL = OutL + (size_t)comp * BM_;
#pragma unroll
    for (int mb = 0; mb < 4; ++mb)
#pragma unroll
        for (int nb = 0; nb < 4; ++nb) {
            int row = m0 + wm * 64 + mb * 16 + (lane >> 4) * 4;
            int col = n0 + wn * 64 + nb * 16 + (lane & 15);
#pragma unroll
            for (int r = 0; r < 4; ++r) {
                CR[(size_t)(row + r) * FF + col] = accR[mb][nb][r];
                CL[(size_t)(row + r) * FF + col] = f2bf(accL[mb][nb][r]);
            }
        }
}

// ---------------- kernel 4: normalize(right) + Cayley gp + left + bias, scale ------
// 2-way b-paired (round-7 proven local optimum: VGPR-lean, latency-bound balance)
__global__ __launch_bounds__(256) void k_gp(const float* __restrict__ x,
                                            const float* __restrict__ OutR,
                                            const ushort* __restrict__ OutL,
                                            const float* __restrict__ gpwT,
                                            const float* __restrict__ sigT,
                                            const float* __restrict__ b_left,
                                            float* __restrict__ out) {
    const int t0 = blockIdx.x * 256 + threadIdx.x;  // 0 .. BM_/2-1
    const int n = t0 & (FF - 1);

    float pw[35];
#pragma unroll
    for (int p = 0; p < 35; ++p) pw[p] = gpwT[(size_t)p * FF + n];
    float sg[5];
#pragma unroll
    for (int g = 0; g < 5; ++g) sg[g] = sigT[(size_t)g * FF + n];
    const float bl = b_left[n];

#pragma unroll
    for (int u = 0; u < 2; ++u) {
        const int bn = t0 + u * (BM_ / 2);

        float xi[16];
        {
            const float4* xp = (const float4*)(x + (size_t)bn * 16);
#pragma unroll
            for (int j = 0; j < 4; ++j) {
                float4 t = xp[j];
                xi[j * 4 + 0] = t.x; xi[j * 4 + 1] = t.y; xi[j * 4 + 2] = t.z; xi[j * 4 + 3] = t.w;
            }
        }

        float R[16];
#pragma unroll
        for (int i = 0; i < 16; ++i) R[i] = OutR[(size_t)i * BM_ + bn];

        float q[5] = {0.f, 0.f, 0.f, 0.f, 0.f};
#pragma unroll
        for (int i = 0; i < 16; ++i) q[TBL.grade[i]] += TBL.beta[i] * R[i] * R[i];
        float inv[5];
#pragma unroll
        for (int g = 0; g < 5; ++g) {
            float nr = sqrtf(fabsf(q[g]));
            float nf = sg[g] * (nr - 1.f) + 1.f + 1e-6f;
            inv[g] = 1.f / nf;
        }
#pragma unroll
        for (int i = 0; i < 16; ++i) R[i] *= inv[TBL.grade[i]];

        float acc[16] = {};
#pragma unroll
        for (int ii = 0; ii < 16; ++ii) {
#pragma unroll
            for (int kk = 0; kk < 16; ++kk) {
                const int j = TBL.jid[ii][kk];
                const int p = TBL.pid[ii][kk];
                const float s = TBL.sgn[ii][kk];
                acc[j] += (s * pw[p]) * (xi[ii] * R[kk]);
            }
        }

        float o[16];
#pragma unroll
        for (int j = 0; j < 16; ++j) {
            float l = bf2f(OutL[(size_t)j * BM_ + bn]);
            if (j == 0) l += bl;
            o[j] = (l + acc[j]) * 0.70710678118654752440f;
        }
        float4* op = (float4*)(out + (size_t)bn * 16);
#pragma unroll
        for (int j = 0; j < 4; ++j) {
            float4 t;
            t.x = o[j * 4 + 0]; t.y = o[j * 4 + 1]; t.z = o[j * 4 + 2]; t.w = o[j * 4 + 3];
            op[j] = t;
        }
    }
}

extern "C" void kernel_launch(void* const* d_in, const int* in_sizes, int n_in,
                              void* d_out, int out_size, void* d_ws, size_t ws_size,
                              hipStream_t stream) {
    (void)in_sizes; (void)n_in; (void)out_size; (void)ws_size;
    const float* x       = (const float*)d_in[0];
    const float* w_left  = (const float*)d_in[1];
    const float* b_left  = (const float*)d_in[2];
    const float* w_right = (const float*)d_in[3];
    const float* a_norm  = (const float*)d_in[4];
    const float* gpw     = (const float*)d_in[5];
    float* out = (float*)d_out;

    char* ws = (char*)d_ws;
    ushort* Xh   = (ushort*)ws;                        //  67,108,864 B
    ushort* Xl   = (ushort*)(ws + 67108864);           //  67,108,864 B
    ushort* Wb   = (ushort*)(ws + 134217728);          //   7,864,320 B
    float*  OutR = (float*)(ws + 142082048);           // 134,217,728 B
    ushort* OutL = (ushort*)(ws + 276299776);          //  67,108,864 B
    // gpwT/sigT overwrite the (then-dead) Xh region after k_gemm finishes
    float*  gpwT = (float*)ws;                         //  71,680 B
    float*  sigT = (float*)(ws + 71680);               //  10,240 B

    k_transpose_x<<<4096, 256, 0, stream>>>(x, Xh, Xl);
    k_prep_w<<<512, 256, 0, stream>>>(w_right, w_left, Wb);
    dim3 g(32, 4, 16);
    k_gemm<<<g, 256, 0, stream>>>(Xh, Xl, Wb, OutR, OutL);
    k_prep_tables<<<2, 256, 0, stream>>>(gpw, a_norm, gpwT, sigT);
    k_gp<<<4096, 256, 0, stream>>>(x, OutR, OutL, gpwT, sigT, b_left, out);
}